// Round 2
// baseline (434.091 us; speedup 1.0000x reference)
//
#include <hip/hip_runtime.h>

#define N_NODES 8192
#define D_IN    128
#define D_OUT   64
#define NSPLIT  16

typedef __attribute__((ext_vector_type(8))) short short8;
typedef __attribute__((ext_vector_type(4))) float f32x4;

// fp32 -> bf16 bits, round-to-nearest-even
__device__ __forceinline__ short f2bf(float f) {
    unsigned u = __builtin_bit_cast(unsigned, f);
    u += 0x7fff + ((u >> 16) & 1);
    return (short)(u >> 16);
}
// pack two fp32 -> two bf16 in one uint (lo in [15:0], hi in [31:16])
__device__ __forceinline__ unsigned f2bf_pack(float lo, float hi) {
    unsigned a = __builtin_bit_cast(unsigned, lo);
    a += 0x7fff + ((a >> 16) & 1);
    unsigned b = __builtin_bit_cast(unsigned, hi);
    b += 0x7fff + ((b >> 16) & 1);
    return (a >> 16) | (b & 0xffff0000u);
}

// ---- Kernel 1: dis[i] = rsqrt(rowsum(A[i,:])); also emit A16 = bf16(A) ----
// One wave per row; 2048 blocks x 256. Sum uses ORIGINAL fp32 values.
__global__ __launch_bounds__(256) void k_deg(const float* __restrict__ A,
                                             float* __restrict__ dis,
                                             unsigned short* __restrict__ A16) {
    const int wave = threadIdx.x >> 6;
    const int lane = threadIdx.x & 63;
    const int row  = blockIdx.x * 4 + wave;
    const float4* Ar = (const float4*)(A + (size_t)row * N_NODES);
    uint2* Aw = (uint2*)(A16 + (size_t)row * N_NODES);
    float s = 0.f;
#pragma unroll
    for (int i = 0; i < 32; ++i) {
        float4 v = Ar[lane + 64 * i];
        s += (v.x + v.y) + (v.z + v.w);
        uint2 p;
        p.x = f2bf_pack(v.x, v.y);
        p.y = f2bf_pack(v.z, v.w);
        Aw[lane + 64 * i] = p;
    }
#pragma unroll
    for (int off = 32; off; off >>= 1) s += __shfl_down(s, off, 64);
    if (lane == 0) dis[row] = rsqrtf(s);
}

// ---- Kernel 2: G = (diag(dis)*X) @ W, packed in MFMA B-frag order (verified R1)
// Gp layout: [ktile t][ntile u][lane][j] bf16; k=(t,quad,j), n=(u,l15), lane=quad*16+(n&15)
__global__ __launch_bounds__(256) void k_gpack(const float* __restrict__ X,
                                               const float* __restrict__ W,
                                               const float* __restrict__ dis,
                                               unsigned short* __restrict__ Gp) {
    __shared__ float Wl[D_IN * D_OUT];
    __shared__ float Xl[32 * 129];
    const int t = blockIdx.x, tid = threadIdx.x;

    const float4* W4 = (const float4*)W;
    float4* Wl4 = (float4*)Wl;
#pragma unroll
    for (int i = 0; i < 8; ++i) Wl4[tid + 256 * i] = W4[tid + 256 * i];
    const float4* X4 = (const float4*)(X + (size_t)t * 32 * D_IN);
#pragma unroll
    for (int i = 0; i < 4; ++i) {
        int idx = tid + 256 * i;
        float4 v = X4[idx];
        int r = idx >> 5, c = (idx & 31) * 4;
        float* dst = Xl + r * 129 + c;
        dst[0] = v.x; dst[1] = v.y; dst[2] = v.z; dst[3] = v.w;
    }
    __syncthreads();

    const int kl = tid & 31;
    const int nb = (tid >> 5) * 8;
    float acc[8] = {0.f,0.f,0.f,0.f,0.f,0.f,0.f,0.f};
    const float* xr = Xl + kl * 129;
    for (int d = 0; d < D_IN; ++d) {
        float xv = xr[d];
        const float* wr = Wl + d * D_OUT + nb;
#pragma unroll
        for (int c = 0; c < 8; ++c) acc[c] += xv * wr[c];
    }
    const float scale = dis[t * 32 + kl];
    const int quad = kl >> 3, j = kl & 7;
#pragma unroll
    for (int c = 0; c < 8; ++c) {
        int n = nb + c;
        int u = n >> 4;
        int lanei = quad * 16 + (n & 15);
        Gp[(((size_t)t * 4 + u) * 64 + lanei) * 8 + j] = (unsigned short)f2bf(acc[c] * scale);
    }
}

// ---- Kernel 3: partial[split] = A16_chunk @ G (bf16 MFMA, plain stores) ----
// Block = 4 waves x 2 row-tiles = 128 rows. Grid (64 row-blocks, NSPLIT).
__global__ __launch_bounds__(256) void k_spmm(const unsigned short* __restrict__ A16,
                                              const unsigned short* __restrict__ Gp,
                                              float* __restrict__ partial) {
    const int lane = threadIdx.x & 63;
    const int wave = threadIdx.x >> 6;
    const int quad = lane >> 4;
    const int l15  = lane & 15;
    const int rowbase = blockIdx.x * 128 + wave * 32;

    // A fragment: lane holds A[row=l15][k=quad*8+j]; one short8 = 16B aligned
    const short8* Ar0 = (const short8*)(A16 + (size_t)(rowbase + l15) * N_NODES);
    const short8* Ar1 = (const short8*)(A16 + (size_t)(rowbase + 16 + l15) * N_NODES);
    const short8* Gq  = (const short8*)Gp;

    const int kt0 = blockIdx.y * (N_NODES / 32 / NSPLIT);   // 16 ktiles per split
    f32x4 acc[2][4] = {};

    for (int kt = kt0; kt < kt0 + (N_NODES / 32 / NSPLIT); ++kt) {
        short8 a0 = Ar0[kt * 4 + quad];
        short8 a1 = Ar1[kt * 4 + quad];
        const short8* gb = Gq + (size_t)kt * 256 + lane;
#pragma unroll
        for (int u = 0; u < 4; ++u) {
            short8 b = gb[u * 64];
            acc[0][u] = __builtin_amdgcn_mfma_f32_16x16x32_bf16(a0, b, acc[0][u], 0, 0, 0);
            acc[1][u] = __builtin_amdgcn_mfma_f32_16x16x32_bf16(a1, b, acc[1][u], 0, 0, 0);
        }
    }

    float* P = partial + (size_t)blockIdx.y * (N_NODES * D_OUT);
#pragma unroll
    for (int rt = 0; rt < 2; ++rt)
#pragma unroll
        for (int u = 0; u < 4; ++u)
#pragma unroll
            for (int r = 0; r < 4; ++r) {
                int gr = rowbase + rt * 16 + quad * 4 + r;
                P[(size_t)gr * D_OUT + u * 16 + l15] = acc[rt][u][r];
            }
}

// ---- Kernel 4: out = relu(dis[row] * sum_s partial[s]) ----
__global__ __launch_bounds__(256) void k_out(const float* __restrict__ partial,
                                             const float* __restrict__ dis,
                                             float* __restrict__ out) {
    const int idx = blockIdx.x * 256 + threadIdx.x;   // float4 index, 131072 total
    const float4* p4 = (const float4*)partial;
    float4 s = p4[idx];
#pragma unroll
    for (int sp = 1; sp < NSPLIT; ++sp) {
        float4 v = p4[idx + sp * (N_NODES * D_OUT / 4)];
        s.x += v.x; s.y += v.y; s.z += v.z; s.w += v.w;
    }
    const float sc = dis[idx >> 4];   // 16 float4 per 64-col row
    float4 o;
    o.x = fmaxf(s.x * sc, 0.f);
    o.y = fmaxf(s.y * sc, 0.f);
    o.z = fmaxf(s.z * sc, 0.f);
    o.w = fmaxf(s.w * sc, 0.f);
    ((float4*)out)[idx] = o;
}

extern "C" void kernel_launch(void* const* d_in, const int* in_sizes, int n_in,
                              void* d_out, int out_size, void* d_ws, size_t ws_size,
                              hipStream_t stream) {
    const float* X = (const float*)d_in[0];   // features [8192,128]
    const float* A = (const float*)d_in[1];   // adjacency [8192,8192]
    const float* W = (const float*)d_in[2];   // weight [128,64]
    float* out = (float*)d_out;

    char* ws = (char*)d_ws;
    float*          dis     = (float*)ws;                                // @0,      32 KB
    unsigned short* Gp      = (unsigned short*)(ws + (1u << 20));        // @1 MB,    1 MB
    unsigned short* A16     = (unsigned short*)(ws + (2u << 20));        // @2 MB,  128 MB
    float*          partial = (float*)(ws + (2u << 20) + ((size_t)128 << 20)); // @130 MB, 32 MB

    k_deg  <<<N_NODES / 4, 256, 0, stream>>>(A, dis, A16);
    k_gpack<<<N_NODES / 32, 256, 0, stream>>>(X, W, dis, Gp);
    k_spmm <<<dim3(N_NODES / 128, NSPLIT), 256, 0, stream>>>(A16, Gp, partial);
    k_out  <<<(N_NODES * D_OUT / 4) / 256, 256, 0, stream>>>(partial, dis, out);
}